// Round 1
// baseline (499.504 us; speedup 1.0000x reference)
//
#include <hip/hip_runtime.h>
#include <math.h>

#define NBINS 15
#define ECE_EPS 1e-5f

// Kernel A: one wave (64 lanes) per row.  Row = 100 fp32 = 25 float4 loads.
// Produces 45 global accumulators in g[]:
//   g[0..14]  = sum_coeffs[b]
//   g[15..29] = sum conf*coeff[b]
//   g[30..44] = sum acc*coeff[b]
__global__ __launch_bounds__(256) void ece_accum(const float* __restrict__ logits,
                                                 const int* __restrict__ labels,
                                                 float* __restrict__ g,
                                                 int n_rows) {
    __shared__ float s_acc[3 * NBINS];
    const int tid = threadIdx.x;
    if (tid < 3 * NBINS) s_acc[tid] = 0.0f;
    __syncthreads();

    const int lane = tid & 63;
    const int wave = tid >> 6;
    const int wavesPerBlock = blockDim.x >> 6;              // 4
    const int totalWaves = gridDim.x * wavesPerBlock;
    const float4* __restrict__ lg4 = (const float4*)logits;

    for (int row = blockIdx.x * wavesPerBlock + wave; row < n_rows; row += totalWaves) {
        // ---- load 100 floats: lanes 0..24 read one float4 each ----
        float v0 = -INFINITY, v1 = -INFINITY, v2 = -INFINITY, v3 = -INFINITY;
        if (lane < 25) {
            float4 v = lg4[(long)row * 25 + lane];
            v0 = v.x; v1 = v.y; v2 = v.z; v3 = v.w;
        }
        // ---- local max/argmax (first-occurrence tie-break) ----
        float m = v0; int mi = lane * 4;
        if (v1 > m) { m = v1; mi = lane * 4 + 1; }
        if (v2 > m) { m = v2; mi = lane * 4 + 2; }
        if (v3 > m) { m = v3; mi = lane * 4 + 3; }
        if (lane >= 25) { m = -INFINITY; mi = 1 << 30; }
        // ---- wave butterfly max/argmax (lower index wins ties) ----
        #pragma unroll
        for (int off = 32; off; off >>= 1) {
            float om = __shfl_xor(m, off);
            int   omi = __shfl_xor(mi, off);
            if (om > m || (om == m && omi < mi)) { m = om; mi = omi; }
        }
        // ---- sum exp(x - m) ----
        float s = 0.0f;
        if (lane < 25) {
            s = __expf(v0 - m) + __expf(v1 - m) + __expf(v2 - m) + __expf(v3 - m);
        }
        #pragma unroll
        for (int off = 32; off; off >>= 1) s += __shfl_xor(s, off);

        const float pred = -__logf(s);              // max of log_softmax
        const float conf = (float)mi;               // argmax index as float
        const float lab  = (float)labels[row];
        const float acc  = (pred == lab) ? 1.0f : 0.0f;

        // ---- 15-bin softmax of -(conf - anchor)^2 / 0.01, lanes 0..14 ----
        float diff = -INFINITY;
        if (lane < NBINS) {
            const float a = (float)(2 * lane + 1) * (1.0f / 30.0f);
            const float d = conf - a;
            diff = -(d * d) * 100.0f;
        }
        float dm = diff;
        #pragma unroll
        for (int off = 8; off; off >>= 1) dm = fmaxf(dm, __shfl_xor(dm, off, 16));
        const float e = (lane < NBINS) ? __expf(diff - dm) : 0.0f;
        float es = e;
        #pragma unroll
        for (int off = 8; off; off >>= 1) es += __shfl_xor(es, off, 16);

        if (lane < NBINS) {
            const float coeff = e / es;
            atomicAdd(&s_acc[lane],             coeff);
            atomicAdd(&s_acc[NBINS + lane],     conf * coeff);
            atomicAdd(&s_acc[2 * NBINS + lane], acc * coeff);
        }
    }
    __syncthreads();
    if (tid < 3 * NBINS) atomicAdd(&g[tid], s_acc[tid]);
}

// Kernel B: one wave folds the 45 sums into the scalar ece.
__global__ void ece_final(const float* __restrict__ g, float* __restrict__ out) {
    const int lane = threadIdx.x & 63;
    float sc = (lane < NBINS) ? g[lane] : 0.0f;
    float total = sc;                       // L1 norm of sum_coeffs (nonneg)
    #pragma unroll
    for (int off = 8; off; off >>= 1) total += __shfl_xor(total, off, 16);
    float contrib = 0.0f;
    if (lane < NBINS) {
        const float denom = fmaxf(sc, ECE_EPS);
        const float bc = g[NBINS + lane] / denom;
        const float ba = g[2 * NBINS + lane] / denom;
        const float w  = sc / fmaxf(total, ECE_EPS);
        const float d  = bc - ba;
        contrib = d * d * w;
    }
    #pragma unroll
    for (int off = 8; off; off >>= 1) contrib += __shfl_xor(contrib, off, 16);
    if (lane == 0) out[0] = sqrtf(contrib);
}

extern "C" void kernel_launch(void* const* d_in, const int* in_sizes, int n_in,
                              void* d_out, int out_size, void* d_ws, size_t ws_size,
                              hipStream_t stream) {
    const float* logits = (const float*)d_in[0];
    const int*   labels = (const int*)d_in[1];
    float* g   = (float*)d_ws;
    float* out = (float*)d_out;
    const int n_rows = in_sizes[1];   // labels element count = N

    hipMemsetAsync(g, 0, 3 * NBINS * sizeof(float), stream);
    ece_accum<<<2048, 256, 0, stream>>>(logits, labels, g, n_rows);
    ece_final<<<1, 64, 0, stream>>>(g, out);
}

// Round 2
// 379.792 us; speedup vs baseline: 1.3152x; 1.3152x over previous
//
#include <hip/hip_runtime.h>
#include <math.h>

#define NBINS 15
#define NCLS 100
#define ECE_EPS 1e-5f

// Kernel A: one thread per row, grid-stride. Row = 100 fp32 = 25 float4.
// Builds a 100-entry histogram: g_cnt[c] = #rows with argmax==c,
// g_acc[c] = sum of (pred==label) over those rows (mathematically ~0, kept faithful).
__global__ __launch_bounds__(256) void ece_hist(const float* __restrict__ logits,
                                                const int* __restrict__ labels,
                                                int* __restrict__ g_cnt,
                                                float* __restrict__ g_acc,
                                                int n_rows) {
    __shared__ int   s_cnt[NCLS];
    __shared__ float s_accs[NCLS];
    const int tid = threadIdx.x;
    if (tid < NCLS) { s_cnt[tid] = 0; s_accs[tid] = 0.0f; }
    __syncthreads();

    const float4* __restrict__ lg4 = (const float4*)logits;
    const int stride = gridDim.x * blockDim.x;
    for (int row = blockIdx.x * blockDim.x + tid; row < n_rows; row += stride) {
        // ---- 25 independent float4 loads into registers ----
        float4 v[25];
        const float4* __restrict__ p = lg4 + (long)row * 25;
        #pragma unroll
        for (int j = 0; j < 25; ++j) v[j] = p[j];

        // ---- max/argmax, first-occurrence tie-break (matches jnp.argmax) ----
        float m = -INFINITY; int mi = 0;
        #pragma unroll
        for (int j = 0; j < 25; ++j) {
            if (v[j].x > m) { m = v[j].x; mi = 4 * j;     }
            if (v[j].y > m) { m = v[j].y; mi = 4 * j + 1; }
            if (v[j].z > m) { m = v[j].z; mi = 4 * j + 2; }
            if (v[j].w > m) { m = v[j].w; mi = 4 * j + 3; }
        }

        // ---- sum exp(x - m), 4 partial sums for ILP ----
        float s0 = 0.0f, s1 = 0.0f, s2 = 0.0f, s3 = 0.0f;
        #pragma unroll
        for (int j = 0; j < 25; ++j) {
            s0 += __expf(v[j].x - m);
            s1 += __expf(v[j].y - m);
            s2 += __expf(v[j].z - m);
            s3 += __expf(v[j].w - m);
        }
        const float s = (s0 + s1) + (s2 + s3);

        const float pred = -__logf(s);                 // max of log_softmax (strictly < 0 here)
        const float acc  = (pred == (float)labels[row]) ? 1.0f : 0.0f;

        atomicAdd(&s_cnt[mi], 1);
        if (acc != 0.0f) atomicAdd(&s_accs[mi], acc);  // essentially never taken
    }
    __syncthreads();
    if (tid < NCLS) {
        const int c = s_cnt[tid];
        if (c) atomicAdd(&g_cnt[tid], c);
        const float a = s_accs[tid];
        if (a != 0.0f) atomicAdd(&g_acc[tid], a);
    }
}

// Kernel B: fold the 100-entry histogram into the 15-bin sums and the final scalar.
// coeff(c,b) = softmax_b( -(c - anchor_b)^2 / 0.01 ), identical math to reference.
__global__ void ece_final(const int* __restrict__ g_cnt,
                          const float* __restrict__ g_acc,
                          float* __restrict__ out) {
    __shared__ float s_bins[3 * NBINS];   // [0..14]=sum_coeffs, [15..29]=sum conf*coeff, [30..44]=sum acc*coeff
    const int tid = threadIdx.x;
    if (tid < 3 * NBINS) s_bins[tid] = 0.0f;
    __syncthreads();

    if (tid < NCLS) {
        const float cnt  = (float)g_cnt[tid];
        const float accv = g_acc[tid];
        const float conf = (float)tid;
        float diff[NBINS];
        float dm = -INFINITY;
        #pragma unroll
        for (int b = 0; b < NBINS; ++b) {
            const float a = (float)(2 * b + 1) * (1.0f / 30.0f);
            const float d = conf - a;
            diff[b] = -(d * d) * 100.0f;
            dm = fmaxf(dm, diff[b]);
        }
        float es = 0.0f;
        float e[NBINS];
        #pragma unroll
        for (int b = 0; b < NBINS; ++b) { e[b] = __expf(diff[b] - dm); es += e[b]; }
        const float inv = 1.0f / es;
        #pragma unroll
        for (int b = 0; b < NBINS; ++b) {
            const float coeff = e[b] * inv;
            if (coeff != 0.0f || cnt != 0.0f) {
                atomicAdd(&s_bins[b],             cnt * coeff);
                atomicAdd(&s_bins[NBINS + b],     conf * cnt * coeff);
                atomicAdd(&s_bins[2 * NBINS + b], accv * coeff);
            }
        }
    }
    __syncthreads();

    if (tid == 0) {
        float total = 0.0f;
        #pragma unroll
        for (int b = 0; b < NBINS; ++b) total += fabsf(s_bins[b]);
        const float invw = 1.0f / fmaxf(total, ECE_EPS);
        float ece = 0.0f;
        #pragma unroll
        for (int b = 0; b < NBINS; ++b) {
            const float sc = s_bins[b];
            const float denom = fmaxf(sc, ECE_EPS);
            const float bc = s_bins[NBINS + b] / denom;
            const float ba = s_bins[2 * NBINS + b] / denom;
            const float d  = bc - ba;
            ece += d * d * (sc * invw);
        }
        out[0] = sqrtf(ece);
    }
}

extern "C" void kernel_launch(void* const* d_in, const int* in_sizes, int n_in,
                              void* d_out, int out_size, void* d_ws, size_t ws_size,
                              hipStream_t stream) {
    const float* logits = (const float*)d_in[0];
    const int*   labels = (const int*)d_in[1];
    int*   g_cnt = (int*)d_ws;
    float* g_acc = (float*)((char*)d_ws + NCLS * sizeof(int));
    float* outp  = (float*)d_out;
    const int n_rows = in_sizes[1];   // labels element count = N

    hipMemsetAsync(d_ws, 0, NCLS * (sizeof(int) + sizeof(float)), stream);
    // 1024 blocks x 256 threads = 262144 threads -> exactly 2 rows/thread at N=524288.
    ece_hist<<<1024, 256, 0, stream>>>(logits, labels, g_cnt, g_acc, n_rows);
    ece_final<<<1, 128, 0, stream>>>(g_cnt, g_acc, outp);
}